// Round 10
// baseline (115.391 us; speedup 1.0000x reference)
//
#include <hip/hip_runtime.h>
#include <hip/hip_bf16.h>
#include <cmath>

#define NHEADS 32
#define DIM 128
#define SPLITS 16
#define TILE 32
#define KSPLIT 16
#define QKV_N 4352
#define HID 4096

typedef __attribute__((ext_vector_type(4))) float f32x4;
typedef __attribute__((ext_vector_type(8))) short short8i;
typedef __attribute__((ext_vector_type(4))) short short4i;

__device__ __forceinline__ unsigned short f2bf(float x) {
  __hip_bfloat16 h = __float2bfloat16(x);   // RNE; compiler emits HW cvt
  return *reinterpret_cast<unsigned short*>(&h);
}
__device__ __forceinline__ unsigned int pk2bf(float lo, float hi) {
  return (unsigned)f2bf(lo) | ((unsigned)f2bf(hi) << 16);
}

__device__ __forceinline__ f32x4 mfma16bf16(short4i a, short4i b, f32x4 c) {
#if __has_builtin(__builtin_amdgcn_mfma_f32_16x16x16bf16_1k)
  return __builtin_amdgcn_mfma_f32_16x16x16bf16_1k(a, b, c, 0, 0, 0);
#else
  asm volatile("v_mfma_f32_16x16x16_bf16 %0, %1, %2, %0"
               : "+v"(c) : "v"(a), "v"(b));
  return c;
#endif
}

// C[64,N] partials = A[64,K] @ W[K,N] via bf16 MFMA, fused fp32->bf16 convert.
// grid=(N/64, KSPLIT), block=256 (4 waves; wave w owns rows w*16..w*16+15).
__global__ __launch_bounds__(256, 4) void gemm64_mfma(
    const float* __restrict__ A, const float* __restrict__ W,
    float* __restrict__ P, int N, int K)
{
  __shared__ unsigned short Ab[64][40];   // bf16 A-tile [m][k]
  __shared__ unsigned short Wt[64][40];   // bf16 W-tile transposed [n][k]
  const int t = threadIdx.x;
  const int w = t >> 6, lane = t & 63;
  const int l4 = lane >> 4, l16 = lane & 15;
  const int n0 = blockIdx.x * 64;
  const int KS = K / KSPLIT;
  const int kbase = blockIdx.y * KS;

  const int ar = t >> 2, akq = t & 3;     // A staging: row 0..63, k-oct 0..3
  const int bn = t & 63, bkq = t >> 6;    // B staging: n 0..63, k-oct 0..3

  f32x4 acc[4];
#pragma unroll
  for (int i = 0; i < 4; ++i) acc[i] = (f32x4){0.f, 0.f, 0.f, 0.f};

  float4 a0, a1;
  float bw[8];

#define GLOAD(KC)                                                          \
  {                                                                        \
    const float* ap = A + (size_t)ar * K + kbase + (KC) + akq * 8;         \
    a0 = *(const float4*)ap;                                               \
    a1 = *(const float4*)(ap + 4);                                         \
    const float* wp = W + (size_t)(kbase + (KC) + bkq * 8) * N + n0 + bn;  \
    _Pragma("unroll")                                                      \
    for (int j = 0; j < 8; ++j) bw[j] = wp[(size_t)j * N];                 \
  }

#define SWRITE                                                             \
  {                                                                        \
    unsigned int ua[4] = {pk2bf(a0.x, a0.y), pk2bf(a0.z, a0.w),            \
                          pk2bf(a1.x, a1.y), pk2bf(a1.z, a1.w)};           \
    *(float4*)&Ab[ar][akq * 8] = *(float4*)ua;                             \
    unsigned int ub[4] = {pk2bf(bw[0], bw[1]), pk2bf(bw[2], bw[3]),        \
                          pk2bf(bw[4], bw[5]), pk2bf(bw[6], bw[7])};       \
    *(float4*)&Wt[bn][bkq * 8] = *(float4*)ub;                             \
  }

  GLOAD(0);
  SWRITE;
  __syncthreads();

  for (int kc = 0; kc < KS; kc += 32) {
    const bool pre = (kc + 32 < KS);
    if (pre) GLOAD(kc + 32);

    const short8i af = *(const short8i*)&Ab[w * 16 + l16][l4 * 8];
#pragma unroll
    for (int nt = 0; nt < 4; ++nt) {
      const short8i bf = *(const short8i*)&Wt[nt * 16 + l16][l4 * 8];
      acc[nt] = __builtin_amdgcn_mfma_f32_16x16x32_bf16(af, bf, acc[nt], 0, 0, 0);
    }

    __syncthreads();
    if (pre) {
      SWRITE;
      __syncthreads();
    }
  }

  float* base = P + (size_t)blockIdx.y * 64 * N + n0;
#pragma unroll
  for (int nt = 0; nt < 4; ++nt)
#pragma unroll
    for (int r = 0; r < 4; ++r)
      base[(size_t)(w * 16 + l4 * 4 + r) * N + nt * 16 + l16] = acc[nt][r];
#undef GLOAD
#undef SWRITE
}

__global__ __launch_bounds__(256) void reduce_parts(
    const float* __restrict__ P, float* __restrict__ C, int total)
{
  const int i = (blockIdx.x * 256 + threadIdx.x) * 4;
  if (i >= total) return;
  float4 s = *(const float4*)(P + i);
#pragma unroll
  for (int k = 1; k < KSPLIT; ++k) {
    const float4 v = *(const float4*)(P + (size_t)k * total + i);
    s.x += v.x; s.y += v.y; s.z += v.z; s.w += v.w;
  }
  *(float4*)(C + i) = s;
}

// RoPE in place on q (32 heads) and k row of qkv. grid=64, block=256
__global__ __launch_bounds__(256) void rope_kernel(
    float* __restrict__ qkv, const int* __restrict__ positions)
{
  const int b = blockIdx.x;
  float* row = qkv + (size_t)b * QKV_N;
  const float pos = (float)positions[b];
  for (int it = threadIdx.x; it < 33 * 64; it += 256) {
    const int r = it >> 6, i = it & 63;
    float* x = row + (r < 32 ? r * DIM : HID);
    const float ex = (float)(2 * i) * (1.0f / 128.0f);
    const float inv = 1.0f / powf(10000.0f, ex);
    const float ang = pos * inv;
    const float c = cosf(ang), sn = sinf(ang);
    const float x1 = x[i], x2 = x[i + 64];
    x[i]      = x1 * c - x2 * sn;
    x[i + 64] = x2 * c + x1 * sn;
  }
}

// MFMA flash-decoding attention, barrier-free main loop.
// grid=(64, SPLITS), block=256 (4 waves: hq=w>>1 head-16-block, pq=w&1 pos-16).
// Each wave streams its own 16-position blocks; K/V loaded from global
// DIRECTLY in MFMA fragment layout (no LDS staging, no barriers until the
// end-of-split cross-pq reduction).
__global__ __launch_bounds__(256, 3) void attn_kernel(
    const float* __restrict__ qkv,
    const float* __restrict__ k_cache, const float* __restrict__ v_cache,
    const int* __restrict__ block_tables, const int* __restrict__ context_lens,
    float* __restrict__ pm, float* __restrict__ pl, float* __restrict__ pacc)
{
  const int b = blockIdx.x, s = blockIdx.y;
  const int t = threadIdx.x;
  const int w = t >> 6, lane = t & 63;
  const int hq = w >> 1, pq = w & 1;
  const int l4 = lane >> 4, l16 = lane & 15;
  const int ctx = context_lens[b];
  const int pos = ctx - 1;
  const int chunk = (ctx + SPLITS - 1) / SPLITS;
  const int start = s * chunk;
  const int end = min(start + chunk, ctx);
  const int nt = (end > start) ? ((end - start + TILE - 1) / TILE) : 0;

  __shared__ float red[2][64][36];   // 18.4 KB cross-pq reduction
  __shared__ int bt_lds[24];

  const float* qbase = qkv + (size_t)b * QKV_N;
  const int bt0 = start >> 4;
  if (t < 24) {
    const int idx = bt0 + t;
    bt_lds[t] = (idx < 256) ? block_tables[b * 256 + idx] : 0;
  }
  __syncthreads();   // bt_lds visible

  // Q fragment (B-operand of swapped QK^T): head hq*16+l16, k = l4*8 + ks*32
  const float scale = 0.08838834764831845f;  // 1/sqrt(128)
  short8i qf[4];
  {
    const float* qp0 = qbase + (hq * 16 + l16) * DIM + l4 * 8;
#pragma unroll
    for (int ks = 0; ks < 4; ++ks) {
      const float4 a = *(const float4*)(qp0 + ks * 32);
      const float4 c = *(const float4*)(qp0 + ks * 32 + 4);
      union { unsigned int u[4]; short8i v; } qc;
      qc.u[0] = pk2bf(a.x * scale, a.y * scale);
      qc.u[1] = pk2bf(a.z * scale, a.w * scale);
      qc.u[2] = pk2bf(c.x * scale, c.y * scale);
      qc.u[3] = pk2bf(c.z * scale, c.w * scale);
      qf[ks] = qc.v;
    }
  }

  f32x4 o2[8];
#pragma unroll
  for (int i = 0; i < 8; ++i) o2[i] = (f32x4){0.f, 0.f, 0.f, 0.f};
  float lh = 0.f;

  for (int it = 0; it < nt; ++it) {
    const int t0 = start + it * TILE + pq * 16;   // this wave's 16-pos block

    // ---- K pointer: row = t0 + l16 (fragment row) ----
    int kpos = t0 + l16;
    if (kpos > pos) kpos = pos;
    const float* kp;
    if (kpos == pos) kp = qbase + HID;
    else {
      const int blk = bt_lds[(kpos >> 4) - bt0];
      kp = k_cache + ((size_t)blk * 16 + (kpos & 15)) * DIM;
    }
    // issue K loads first (QK consumes them; V stays in flight under QK)
    float4 kraw[8];
#pragma unroll
    for (int ks = 0; ks < 4; ++ks) {
      kraw[ks * 2 + 0] = *(const float4*)(kp + ks * 32 + l4 * 8);
      kraw[ks * 2 + 1] = *(const float4*)(kp + ks * 32 + l4 * 8 + 4);
    }

    // ---- V pointers: rows t0 + l4*4 + j ----
    const float *vp0, *vp1, *vp2, *vp3;
#define VPTR(J, VP)                                                        \
    {                                                                      \
      int gv = t0 + l4 * 4 + (J);                                          \
      if (gv > pos) gv = pos;                                              \
      if (gv == pos) VP = qbase + HID + DIM;                               \
      else {                                                               \
        const int blk = bt_lds[(gv >> 4) - bt0];                           \
        VP = v_cache + ((size_t)blk * 16 + (gv & 15)) * DIM;               \
      }                                                                    \
    }
    VPTR(0, vp0) VPTR(1, vp1) VPTR(2, vp2) VPTR(3, vp3)
#undef VPTR
    float vraw[8][4];
#pragma unroll
    for (int ob = 0; ob < 8; ++ob) {
      vraw[ob][0] = vp0[ob * 16 + l16];
      vraw[ob][1] = vp1[ob * 16 + l16];
      vraw[ob][2] = vp2[ob * 16 + l16];
      vraw[ob][3] = vp3[ob * 16 + l16];
    }

    // ---- QK^T: D[pos, head] ----
    f32x4 accs = {0.f, 0.f, 0.f, 0.f};
#pragma unroll
    for (int ks = 0; ks < 4; ++ks) {
      union { unsigned int u[4]; short8i v; } kc;
      kc.u[0] = pk2bf(kraw[ks * 2].x,     kraw[ks * 2].y);
      kc.u[1] = pk2bf(kraw[ks * 2].z,     kraw[ks * 2].w);
      kc.u[2] = pk2bf(kraw[ks * 2 + 1].x, kraw[ks * 2 + 1].y);
      kc.u[3] = pk2bf(kraw[ks * 2 + 1].z, kraw[ks * 2 + 1].w);
      accs = __builtin_amdgcn_mfma_f32_16x16x32_bf16(kc.v, qf[ks], accs, 0, 0, 0);
    }

    // ---- exp (no max), mask, denom, pack P as PV A-frag ----
    const int pb_ = t0 + l4 * 4;
    const float p0 = (pb_ + 0 < end) ? __expf(accs[0]) : 0.f;
    const float p1 = (pb_ + 1 < end) ? __expf(accs[1]) : 0.f;
    const float p2 = (pb_ + 2 < end) ? __expf(accs[2]) : 0.f;
    const float p3 = (pb_ + 3 < end) ? __expf(accs[3]) : 0.f;
    lh += (p0 + p1) + (p2 + p3);
    union { unsigned int u[2]; short4i v; } pc;
    pc.u[0] = pk2bf(p0, p1);
    pc.u[1] = pk2bf(p2, p3);
    const short4i pf = pc.v;

    // ---- PV: o2[ob] += P * V ----
#pragma unroll
    for (int ob = 0; ob < 8; ++ob) {
      union { unsigned int u[2]; short4i v; } vc;
      vc.u[0] = pk2bf(vraw[ob][0], vraw[ob][1]);
      vc.u[1] = pk2bf(vraw[ob][2], vraw[ob][3]);
      o2[ob] = mfma16bf16(pf, vc.v, o2[ob]);
    }
  }

  // ---- end of split: reduce denom within wave, combine pq halves via LDS ----
  float lhr = lh;
  lhr += __shfl_xor(lhr, 16);
  lhr += __shfl_xor(lhr, 32);

  if (pq == 1) {
#pragma unroll
    for (int ob = 0; ob < 8; ++ob) *(f32x4*)&red[hq][lane][ob * 4] = o2[ob];
    red[hq][lane][32] = lhr;
  }
  __syncthreads();
  if (pq == 0) {
#pragma unroll
    for (int ob = 0; ob < 8; ++ob) {
      const f32x4 r4 = *(const f32x4*)&red[hq][lane][ob * 4];
      o2[ob] += r4;
    }
    lhr += red[hq][lane][32];
    const size_t sbase = (size_t)(b * SPLITS + s) * NHEADS + hq * 16;
#pragma unroll
    for (int ob = 0; ob < 8; ++ob) {
      pacc[(sbase + l4 * 4 + 0) * DIM + ob * 16 + l16] = o2[ob][0];
      pacc[(sbase + l4 * 4 + 1) * DIM + ob * 16 + l16] = o2[ob][1];
      pacc[(sbase + l4 * 4 + 2) * DIM + ob * 16 + l16] = o2[ob][2];
      pacc[(sbase + l4 * 4 + 3) * DIM + ob * 16 + l16] = o2[ob][3];
    }
    if (lane < 16) { pm[sbase + lane] = 0.f; pl[sbase + lane] = lhr; }
  }
}

// combine partials -> attn[b][h*128+d]. grid=2048, block=128
__global__ __launch_bounds__(128) void combine_kernel(
    const float* __restrict__ pm, const float* __restrict__ pl,
    const float* __restrict__ pacc, float* __restrict__ attn)
{
  const int bh = blockIdx.x;
  const int b = bh >> 5, h = bh & 31;
  const int d = threadIdx.x;
  float ms[SPLITS], ls[SPLITS];
  float M = -1e30f;
#pragma unroll
  for (int s = 0; s < SPLITS; ++s) {
    ms[s] = pm[(size_t)(b * SPLITS + s) * NHEADS + h];
    ls[s] = pl[(size_t)(b * SPLITS + s) * NHEADS + h];
    M = fmaxf(M, ms[s]);
  }
  float L = 0.f, o = 0.f;
#pragma unroll
  for (int s = 0; s < SPLITS; ++s) {
    const float wgt = __expf(ms[s] - M);
    L += ls[s] * wgt;
    o += wgt * pacc[((size_t)(b * SPLITS + s) * NHEADS + h) * DIM + d];
  }
  attn[(size_t)b * HID + h * DIM + d] = o / L;
}

extern "C" void kernel_launch(void* const* d_in, const int* in_sizes, int n_in,
                              void* d_out, int out_size, void* d_ws, size_t ws_size,
                              hipStream_t stream) {
  const float* hidden   = (const float*)d_in[0];
  const float* wqkv     = (const float*)d_in[1];
  const float* wdense   = (const float*)d_in[2];
  const float* k_cache  = (const float*)d_in[3];
  const float* v_cache  = (const float*)d_in[4];
  const int* positions    = (const int*)d_in[5];   // integer inputs arrive as int32
  const int* block_tables = (const int*)d_in[6];
  const int* context_lens = (const int*)d_in[7];
  float* out = (float*)d_out;

  float* qkv  = (float*)d_ws;                 // 64*4352
  float* attn = qkv + 64 * QKV_N;             // 64*4096
  // union region: gp (GEMM partials, 16*64*4352 fl) aliases pacc/pm/pl
  float* un   = attn + 64 * HID;
  float* gp   = un;
  float* pacc = un;
  float* pm   = pacc + (size_t)64 * SPLITS * NHEADS * DIM;
  float* pl   = pm + 64 * SPLITS * NHEADS;

  // 1) qkv = hidden @ wqkv  (bf16 MFMA, fused convert)
  gemm64_mfma<<<dim3(QKV_N / 64, KSPLIT), 256, 0, stream>>>(hidden, wqkv, gp, QKV_N, HID);
  reduce_parts<<<(64 * QKV_N) / 1024, 256, 0, stream>>>(gp, qkv, 64 * QKV_N);
  // 2) RoPE on q and k
  rope_kernel<<<64, 256, 0, stream>>>(qkv, positions);
  // 3) attention (MFMA flash-decoding, barrier-free streaming)
  attn_kernel<<<dim3(64, SPLITS), 256, 0, stream>>>(qkv, k_cache, v_cache,
                                                    block_tables, context_lens, pm, pl, pacc);
  combine_kernel<<<64 * NHEADS, 128, 0, stream>>>(pm, pl, pacc, attn);
  // 4) out = attn @ wdense  (bf16 MFMA, fused convert)
  gemm64_mfma<<<dim3(HID / 64, KSPLIT), 256, 0, stream>>>(attn, wdense, gp, HID, HID);
  reduce_parts<<<(64 * HID) / 1024, 256, 0, stream>>>(gp, out, 64 * HID);
}

// Round 11
// 109.793 us; speedup vs baseline: 1.0510x; 1.0510x over previous
//
#include <hip/hip_runtime.h>
#include <hip/hip_bf16.h>
#include <cmath>

#define NHEADS 32
#define DIM 128
#define SPLITS 32          // fixed 128-pos windows: 32*128 = 4096 max ctx
#define WIN 128
#define TILE 32
#define KSPLIT 16
#define QKV_N 4352
#define HID 4096

typedef __attribute__((ext_vector_type(4))) float f32x4;
typedef __attribute__((ext_vector_type(8))) short short8i;
typedef __attribute__((ext_vector_type(4))) short short4i;

__device__ __forceinline__ unsigned short f2bf(float x) {
  __hip_bfloat16 h = __float2bfloat16(x);   // RNE; HW cvt
  return *reinterpret_cast<unsigned short*>(&h);
}
__device__ __forceinline__ unsigned int pk2bf(float lo, float hi) {
  return (unsigned)f2bf(lo) | ((unsigned)f2bf(hi) << 16);
}
__device__ __forceinline__ float bf2f(unsigned short u) {
  unsigned int b = ((unsigned int)u) << 16;
  return __uint_as_float(b);
}

__device__ __forceinline__ f32x4 mfma16bf16(short4i a, short4i b, f32x4 c) {
#if __has_builtin(__builtin_amdgcn_mfma_f32_16x16x16bf16_1k)
  return __builtin_amdgcn_mfma_f32_16x16x16bf16_1k(a, b, c, 0, 0, 0);
#else
  asm volatile("v_mfma_f32_16x16x16_bf16 %0, %1, %2, %0"
               : "+v"(c) : "v"(a), "v"(b));
  return c;
#endif
}

// C[64,N] partials = A[64,K] @ W[K,N] via bf16 MFMA, fused fp32->bf16 convert.
// grid=(N/64, KSPLIT), block=256 (4 waves; wave w owns rows w*16..w*16+15).
__global__ __launch_bounds__(256, 4) void gemm64_mfma(
    const float* __restrict__ A, const float* __restrict__ W,
    float* __restrict__ P, int N, int K)
{
  __shared__ unsigned short Ab[64][40];   // bf16 A-tile [m][k]
  __shared__ unsigned short Wt[64][40];   // bf16 W-tile transposed [n][k]
  const int t = threadIdx.x;
  const int w = t >> 6, lane = t & 63;
  const int l4 = lane >> 4, l16 = lane & 15;
  const int n0 = blockIdx.x * 64;
  const int KS = K / KSPLIT;
  const int kbase = blockIdx.y * KS;

  const int ar = t >> 2, akq = t & 3;     // A staging: row 0..63, k-oct 0..3
  const int bn = t & 63, bkq = t >> 6;    // B staging: n 0..63, k-oct 0..3

  f32x4 acc[4];
#pragma unroll
  for (int i = 0; i < 4; ++i) acc[i] = (f32x4){0.f, 0.f, 0.f, 0.f};

  float4 a0, a1;
  float bw[8];

#define GLOAD(KC)                                                          \
  {                                                                        \
    const float* ap = A + (size_t)ar * K + kbase + (KC) + akq * 8;         \
    a0 = *(const float4*)ap;                                               \
    a1 = *(const float4*)(ap + 4);                                         \
    const float* wp = W + (size_t)(kbase + (KC) + bkq * 8) * N + n0 + bn;  \
    _Pragma("unroll")                                                      \
    for (int j = 0; j < 8; ++j) bw[j] = wp[(size_t)j * N];                 \
  }

#define SWRITE                                                             \
  {                                                                        \
    unsigned int ua[4] = {pk2bf(a0.x, a0.y), pk2bf(a0.z, a0.w),            \
                          pk2bf(a1.x, a1.y), pk2bf(a1.z, a1.w)};           \
    *(float4*)&Ab[ar][akq * 8] = *(float4*)ua;                             \
    unsigned int ub[4] = {pk2bf(bw[0], bw[1]), pk2bf(bw[2], bw[3]),        \
                          pk2bf(bw[4], bw[5]), pk2bf(bw[6], bw[7])};       \
    *(float4*)&Wt[bn][bkq * 8] = *(float4*)ub;                             \
  }

  GLOAD(0);
  SWRITE;
  __syncthreads();

  for (int kc = 0; kc < KS; kc += 32) {
    const bool pre = (kc + 32 < KS);
    if (pre) GLOAD(kc + 32);

    const short8i af = *(const short8i*)&Ab[w * 16 + l16][l4 * 8];
#pragma unroll
    for (int nt = 0; nt < 4; ++nt) {
      const short8i bf = *(const short8i*)&Wt[nt * 16 + l16][l4 * 8];
      acc[nt] = __builtin_amdgcn_mfma_f32_16x16x32_bf16(af, bf, acc[nt], 0, 0, 0);
    }

    __syncthreads();
    if (pre) {
      SWRITE;
      __syncthreads();
    }
  }

  float* base = P + (size_t)blockIdx.y * 64 * N + n0;
#pragma unroll
  for (int nt = 0; nt < 4; ++nt)
#pragma unroll
    for (int r = 0; r < 4; ++r)
      base[(size_t)(w * 16 + l4 * 4 + r) * N + nt * 16 + l16] = acc[nt][r];
#undef GLOAD
#undef SWRITE
}

__global__ __launch_bounds__(256) void reduce_parts(
    const float* __restrict__ P, float* __restrict__ C, int total)
{
  const int i = (blockIdx.x * 256 + threadIdx.x) * 4;
  if (i >= total) return;
  float4 s = *(const float4*)(P + i);
#pragma unroll
  for (int k = 1; k < KSPLIT; ++k) {
    const float4 v = *(const float4*)(P + (size_t)k * total + i);
    s.x += v.x; s.y += v.y; s.z += v.z; s.w += v.w;
  }
  *(float4*)(C + i) = s;
}

// RoPE in place on q (32 heads) and k row of qkv. grid=64, block=256
__global__ __launch_bounds__(256) void rope_kernel(
    float* __restrict__ qkv, const int* __restrict__ positions)
{
  const int b = blockIdx.x;
  float* row = qkv + (size_t)b * QKV_N;
  const float pos = (float)positions[b];
  for (int it = threadIdx.x; it < 33 * 64; it += 256) {
    const int r = it >> 6, i = it & 63;
    float* x = row + (r < 32 ? r * DIM : HID);
    const float ex = (float)(2 * i) * (1.0f / 128.0f);
    const float inv = 1.0f / powf(10000.0f, ex);
    const float ang = pos * inv;
    const float c = cosf(ang), sn = sinf(ang);
    const float x1 = x[i], x2 = x[i + 64];
    x[i]      = x1 * c - x2 * sn;
    x[i + 64] = x2 * c + x1 * sn;
  }
}

// MFMA flash-decoding attention, fixed 128-pos windows with early exit.
// grid=(64, 32), block=256 (4 waves: hq=w>>1 head-16-block, pq=w&1 pos-16).
// LDS-staged K (XOR-swizzled) / V (transposed), no-max softmax, bf16 pacc.
__global__ __launch_bounds__(256, 4) void attn_kernel(
    const float* __restrict__ qkv,
    const float* __restrict__ k_cache, const float* __restrict__ v_cache,
    const int* __restrict__ block_tables, const int* __restrict__ context_lens,
    float* __restrict__ pl, unsigned short* __restrict__ pacc)
{
  const int b = blockIdx.x, s = blockIdx.y;
  const int ctx = context_lens[b];
  const int start = s * WIN;
  if (start >= ctx) return;                 // uniform early exit
  const int end = min(start + WIN, ctx);
  const int pos = ctx - 1;
  const int nt = (end - start + TILE - 1) / TILE;   // 1..4 tiles

  const int t = threadIdx.x;
  const int w = t >> 6, lane = t & 63;
  const int hq = w >> 1, pq = w & 1;
  const int l4 = lane >> 4, l16 = lane & 15;

  __shared__ unsigned short KbU[32 * 128];   // 8 KB bf16 K, XOR-swizzled 16B units
  __shared__ unsigned short VtU[128 * 34];   // 8.5 KB bf16 V transposed [od][pos]
  __shared__ float red[2][64][36];           // 18.4 KB cross-pq reduction
  __shared__ int bt_lds[8];                  // 8 KV blocks per 128-pos window

  const float* qbase = qkv + (size_t)b * QKV_N;
  const int bt0 = start >> 4;
  if (t < 8) {
    const int idx = bt0 + t;
    bt_lds[t] = (idx < 256) ? block_tables[b * 256 + idx] : 0;
  }

  const float scale = 0.08838834764831845f;  // 1/sqrt(128)
  short8i qf[4];
  {
    const float* qp0 = qbase + (hq * 16 + l16) * DIM + l4 * 8;
#pragma unroll
    for (int ks = 0; ks < 4; ++ks) {
      const float4 a = *(const float4*)(qp0 + ks * 32);
      const float4 c = *(const float4*)(qp0 + ks * 32 + 4);
      union { unsigned int u[4]; short8i v; } qc;
      qc.u[0] = pk2bf(a.x * scale, a.y * scale);
      qc.u[1] = pk2bf(a.z * scale, a.w * scale);
      qc.u[2] = pk2bf(c.x * scale, c.y * scale);
      qc.u[3] = pk2bf(c.z * scale, c.w * scale);
      qf[ks] = qc.v;
    }
  }

  f32x4 o2[8];
#pragma unroll
  for (int i = 0; i < 8; ++i) o2[i] = (f32x4){0.f, 0.f, 0.f, 0.f};
  float lh = 0.f;

  float4 kreg[4], vreg[4];
  const int tk_sub = t >> 5;   // 0..7
  const int tk_col = t & 31;   // 0..31

#define LOADREGS(T0)                                                     \
  {                                                                      \
    _Pragma("unroll")                                                    \
    for (int j = 0; j < 4; ++j) {                                        \
      int gp_ = (T0) + j * 8 + tk_sub;                                   \
      if (gp_ > pos) gp_ = pos;                                          \
      const float* kp;                                                   \
      if (gp_ == pos) kp = qbase + HID;                                  \
      else {                                                             \
        const int blk = bt_lds[(gp_ >> 4) - bt0];                        \
        kp = k_cache + ((size_t)blk * 16 + (gp_ & 15)) * DIM;            \
      }                                                                  \
      kreg[j] = *(const float4*)(kp + tk_col * 4);                       \
    }                                                                    \
    int gv = (T0) + tk_col;                                              \
    if (gv > pos) gv = pos;                                              \
    const float* vp;                                                     \
    if (gv == pos) vp = qbase + HID + DIM;                               \
    else {                                                               \
      const int blk = bt_lds[(gv >> 4) - bt0];                           \
      vp = v_cache + ((size_t)blk * 16 + (gv & 15)) * DIM;               \
    }                                                                    \
    _Pragma("unroll")                                                    \
    for (int j = 0; j < 4; ++j)                                          \
      vreg[j] = *(const float4*)(vp + tk_sub * 16 + j * 4);              \
  }

#define WRITE_TILE                                                                     \
  {                                                                                    \
    _Pragma("unroll")                                                                  \
    for (int j = 0; j < 4; ++j) {                                                      \
      const int pl_ = j * 8 + tk_sub;                                                  \
      const int up = (tk_col >> 1) ^ (pl_ & 15);                                       \
      unsigned int lo = pk2bf(kreg[j].x, kreg[j].y);                                   \
      unsigned int hi = pk2bf(kreg[j].z, kreg[j].w);                                   \
      unsigned int* dst = (unsigned int*)&KbU[pl_ * 128 + up * 8 + (tk_col & 1) * 4];  \
      dst[0] = lo; dst[1] = hi;                                                        \
    }                                                                                  \
    _Pragma("unroll")                                                                  \
    for (int j = 0; j < 4; ++j) {                                                      \
      const int od0 = tk_sub * 16 + j * 4;                                             \
      VtU[(od0 + 0) * 34 + tk_col] = f2bf(vreg[j].x);                                  \
      VtU[(od0 + 1) * 34 + tk_col] = f2bf(vreg[j].y);                                  \
      VtU[(od0 + 2) * 34 + tk_col] = f2bf(vreg[j].z);                                  \
      VtU[(od0 + 3) * 34 + tk_col] = f2bf(vreg[j].w);                                  \
    }                                                                                  \
  }

  __syncthreads();             // bt_lds visible
  LOADREGS(start);
  WRITE_TILE;
  __syncthreads();

  for (int it = 0; it < nt; ++it) {
    const int t0 = start + it * TILE;
    const bool pre = (it + 1 < nt);
    if (pre) LOADREGS(t0 + TILE);    // loads in flight under compute

    // ---- QK^T: D[pos,head] over this wave's quadrant ----
    f32x4 accs = {0.f, 0.f, 0.f, 0.f};
    const int rowK = pq * 16 + l16;
#pragma unroll
    for (int ks = 0; ks < 4; ++ks) {
      const int up = (l4 + ks * 4) ^ l16;
      const short8i kf = *(const short8i*)&KbU[rowK * 128 + up * 8];
      accs = __builtin_amdgcn_mfma_f32_16x16x32_bf16(kf, qf[ks], accs, 0, 0, 0);
    }

    // ---- exp (no max), mask, per-lane denom, pack P as PV A-frag ----
    const int pb_ = t0 + pq * 16 + l4 * 4;
    const float p0 = (pb_ + 0 < end) ? __expf(accs[0]) : 0.f;
    const float p1 = (pb_ + 1 < end) ? __expf(accs[1]) : 0.f;
    const float p2 = (pb_ + 2 < end) ? __expf(accs[2]) : 0.f;
    const float p3 = (pb_ + 3 < end) ? __expf(accs[3]) : 0.f;
    lh += (p0 + p1) + (p2 + p3);
    union { unsigned int u[2]; short4i v; } pc;
    pc.u[0] = pk2bf(p0, p1);
    pc.u[1] = pk2bf(p2, p3);
    const short4i pf = pc.v;

    // ---- PV: o2[ob] += P * V over this wave's 16 positions ----
    const int vb = pq * 16 + l4 * 4;
#pragma unroll
    for (int ob = 0; ob < 8; ++ob) {
      const int rowV = ob * 16 + l16;
      union { unsigned int u[2]; short4i v; } vc;
      vc.u[0] = *(const unsigned int*)&VtU[rowV * 34 + vb];
      vc.u[1] = *(const unsigned int*)&VtU[rowV * 34 + vb + 2];
      o2[ob] = mfma16bf16(pf, vc.v, o2[ob]);
    }

    if (pre) {
      __syncthreads();
      WRITE_TILE;
      __syncthreads();
    }
  }

  // ---- end of window: reduce denom, combine pq halves via LDS ----
  float lhr = lh;
  lhr += __shfl_xor(lhr, 16);
  lhr += __shfl_xor(lhr, 32);

  if (pq == 1) {
#pragma unroll
    for (int ob = 0; ob < 8; ++ob) *(f32x4*)&red[hq][lane][ob * 4] = o2[ob];
    red[hq][lane][32] = lhr;
  }
  __syncthreads();
  if (pq == 0) {
#pragma unroll
    for (int ob = 0; ob < 8; ++ob) {
      const f32x4 r4 = *(const f32x4*)&red[hq][lane][ob * 4];
      o2[ob] += r4;
    }
    lhr += red[hq][lane][32];
    const size_t sbase = (size_t)(b * SPLITS + s) * NHEADS + hq * 16;
#pragma unroll
    for (int ob = 0; ob < 8; ++ob) {
      pacc[(sbase + l4 * 4 + 0) * DIM + ob * 16 + l16] = f2bf(o2[ob][0]);
      pacc[(sbase + l4 * 4 + 1) * DIM + ob * 16 + l16] = f2bf(o2[ob][1]);
      pacc[(sbase + l4 * 4 + 2) * DIM + ob * 16 + l16] = f2bf(o2[ob][2]);
      pacc[(sbase + l4 * 4 + 3) * DIM + ob * 16 + l16] = f2bf(o2[ob][3]);
    }
    if (lane < 16) pl[sbase + lane] = lhr;
  }
#undef LOADREGS
#undef WRITE_TILE
}

// combine partials -> attn[b][h*128+d]. grid=2048, block=128.
// No-max softmax => equal split weights: out = sum(pacc)/sum(pl) over active.
__global__ __launch_bounds__(128) void combine_kernel(
    const float* __restrict__ pl, const unsigned short* __restrict__ pacc,
    const int* __restrict__ context_lens, float* __restrict__ attn)
{
  const int bh = blockIdx.x;
  const int b = bh >> 5, h = bh & 31;
  const int d = threadIdx.x;
  const int ctx = context_lens[b];
  const int ns = (ctx + WIN - 1) / WIN;
  float L = 0.f, o = 0.f;
  for (int s = 0; s < ns; ++s) {
    const size_t idx = (size_t)(b * SPLITS + s) * NHEADS + h;
    L += pl[idx];
    o += bf2f(pacc[idx * DIM + d]);
  }
  attn[(size_t)b * HID + h * DIM + d] = o / L;
}

extern "C" void kernel_launch(void* const* d_in, const int* in_sizes, int n_in,
                              void* d_out, int out_size, void* d_ws, size_t ws_size,
                              hipStream_t stream) {
  const float* hidden   = (const float*)d_in[0];
  const float* wqkv     = (const float*)d_in[1];
  const float* wdense   = (const float*)d_in[2];
  const float* k_cache  = (const float*)d_in[3];
  const float* v_cache  = (const float*)d_in[4];
  const int* positions    = (const int*)d_in[5];   // integer inputs arrive as int32
  const int* block_tables = (const int*)d_in[6];
  const int* context_lens = (const int*)d_in[7];
  float* out = (float*)d_out;

  float* qkv  = (float*)d_ws;                 // 64*4352
  float* attn = qkv + 64 * QKV_N;             // 64*4096
  // union region: gp (GEMM partials, 16*64*4352 = 4.46M fl) aliases
  // pacc (bf16, 64*32*32*128 = 4.19M fl-equiv) + pl (65K fl). 4.26M < 4.46M.
  float* un   = attn + 64 * HID;
  float* gp   = un;
  unsigned short* pacc = (unsigned short*)un;
  float* pl   = un + (size_t)64 * SPLITS * NHEADS * DIM / 2;

  // 1) qkv = hidden @ wqkv  (bf16 MFMA, fused convert)
  gemm64_mfma<<<dim3(QKV_N / 64, KSPLIT), 256, 0, stream>>>(hidden, wqkv, gp, QKV_N, HID);
  reduce_parts<<<(64 * QKV_N) / 1024, 256, 0, stream>>>(gp, qkv, 64 * QKV_N);
  // 2) RoPE on q and k
  rope_kernel<<<64, 256, 0, stream>>>(qkv, positions);
  // 3) attention (MFMA flash-decoding, fixed 128-pos windows, early exit)
  attn_kernel<<<dim3(64, SPLITS), 256, 0, stream>>>(qkv, k_cache, v_cache,
                                                    block_tables, context_lens, pl, pacc);
  combine_kernel<<<64 * NHEADS, 128, 0, stream>>>(pl, pacc, context_lens, attn);
  // 4) out = attn @ wdense  (bf16 MFMA, fused convert)
  gemm64_mfma<<<dim3(HID / 64, KSPLIT), 256, 0, stream>>>(attn, wdense, gp, HID, HID);
  reduce_parts<<<(64 * HID) / 1024, 256, 0, stream>>>(gp, out, 64 * HID);
}